// Round 14
// baseline (3052.843 us; speedup 1.0000x reference)
//
#include <hip/hip_runtime.h>
#include <hip/hip_bf16.h>

#define NN 50000
#define NE 800000
#define HD 64
#define OD 16
#define CAP 64        // padded-CSR slots per node
#define TILES 3125    // NN/16
#define AST 72        // LDS A/C row stride in u16 (144 B); 36 u32
#define BCAP 131072   // per-bucket FIFO capacity (mean 100k, +98 sigma)
#define LBLK 6256     // layer grid: 782*8 (2 blocks per tile, XCD-split)

typedef unsigned short u16;
typedef unsigned int u32;
typedef __attribute__((ext_vector_type(8))) short short8;
typedef __attribute__((ext_vector_type(4))) float f32x4;
typedef __attribute__((ext_vector_type(2))) unsigned int u32x2;

__device__ __forceinline__ float bf2f(u16 v) { return __uint_as_float(((u32)v) << 16); }
__device__ __forceinline__ u16 f2bf(float f) {
  __hip_bfloat16 h = __float2bfloat16(f);
  return *reinterpret_cast<u16*>(&h);
}
__device__ __forceinline__ float ldf(const void* p, long i, bool f32m) {
  return f32m ? ((const float*)p)[i] : bf2f(((const u16*)p)[i]);
}
__device__ __forceinline__ int edge_at(const void* eidx, long pos, bool i64) {
  return i64 ? (int)((const long long*)eidx)[pos] : ((const int*)eidx)[pos];
}

// deterministic local dtype detects (same fixed words in every block -> consistent)
__device__ __forceinline__ bool detect_i64(const u32* e32, int lane) {
  return __ballot(e32[2 * lane + 1] != 0u) == 0ull;
}
__device__ __forceinline__ bool detect_f32(const u32* x32, int lane) {
  u32 v = x32[lane] & 0xffffu;
  int e = (int)((v >> 7) & 0xff);
  bool wild = (v != 0u) && (e < 100 || e > 140);
  return __popcll(__ballot(wild)) > 16;
}

// Pass 1: single-pass edge binning into 8 XCD-range FIFOs (one edge read!)
// + conversions (x->bf16 in f32 mode, MFMA B/proj frags, biases).
// grid 3125*256 = 800000 == NE. bucketCnt lives in flags[8..15].
__global__ __launch_bounds__(256) void k_pre(
    const void* __restrict__ x, const void* __restrict__ eidx,
    const void* __restrict__ Wl, const void* __restrict__ bl,
    const void* __restrict__ Wr, const void* __restrict__ Wo,
    const void* __restrict__ bo,
    int* __restrict__ deg, u16* __restrict__ csr, u32* __restrict__ spill,
    u32* __restrict__ bucketBuf,
    u16* __restrict__ xA, u16* __restrict__ wfrag, u16* __restrict__ pfrag,
    float* __restrict__ blf, float* __restrict__ bof,
    int* __restrict__ flags) {
  __shared__ int hist8[8];
  __shared__ int base8[8];
  int lane = threadIdx.x & 63;
  bool i64 = detect_i64((const u32*)eidx, lane);
  bool f32m = detect_f32((const u32*)x, lane);
  int i = blockIdx.x * 256 + threadIdx.x;  // 0..799999

  if (threadIdx.x < 8) hist8[threadIdx.x] = 0;
  __syncthreads();
  int src = edge_at(eidx, i, i64);
  int dst = edge_at(eidx, (long)NE + i, i64);
  int b = dst / 6250;  // 8 buckets of 6250 dst-nodes
  int rank = atomicAdd(&hist8[b], 1);
  __syncthreads();
  if (threadIdx.x < 8)
    base8[threadIdx.x] = atomicAdd(&flags[8 + threadIdx.x], hist8[threadIdx.x]);
  __syncthreads();
  int pos = base8[b] + rank;
  if (pos < BCAP) {
    bucketBuf[(long)b * BCAP + pos] = ((u32)dst << 16) | (u32)src;
  } else {  // adversarial overflow: direct slow path
    int p2 = atomicAdd(&deg[dst], 1);
    if (p2 < CAP) csr[(long)dst * CAP + p2] = (u16)src;
    else {
      int sp = atomicAdd(&flags[4], 1);
      spill[sp] = (u32)dst * 50000u + (u32)src;
    }
  }

  if (f32m) {
    float4 v = ((const float4*)x)[i];
    u32 lo = (u32)f2bf(v.x) | ((u32)f2bf(v.y) << 16);
    u32 hi = (u32)f2bf(v.z) | ((u32)f2bf(v.w) << 16);
    ((u32*)xA)[2 * i] = lo;
    ((u32*)xA)[2 * i + 1] = hi;
  }
  if (i < 3 * 16 * 64 * 8) {  // B frags: k=32s+(lane>>4)*8+j, n=16c+(lane&15)
    int j = i & 7, ln = (i >> 3) & 63, f = (i >> 9) & 15, l = i >> 13;
    int s = f >> 2, c = f & 3;
    int k = 32 * s + ((ln >> 4) << 3) + j;
    int n = (c << 4) + (ln & 15);
    long wbase = (long)l * HD * HD;
    float v = (k < HD) ? ldf(Wl, wbase + (long)k * HD + n, f32m)
                       : ldf(Wr, wbase + (long)(k - HD) * HD + n, f32m);
    wfrag[i] = f2bf(v);
  }
  if (i < 2 * 64 * 8) {  // proj frags
    int j = i & 7, ln = (i >> 3) & 63, s = i >> 9;
    int k = 32 * s + ((ln >> 4) << 3) + j;
    pfrag[i] = f2bf(ldf(Wo, (long)k * OD + (ln & 15), f32m));
  }
  if (i < 3 * HD) blf[i] = ldf(bl, i, f32m);
  if (i < OD) bof[i] = ldf(bo, i, f32m);
}

// Pass 2: XCD-local scatter. bucket = blockIdx&7 (consecutive blockIdx
// round-robins XCDs) -> each bucket's 800 KB CSR span stays in ONE L2.
__global__ __launch_bounds__(256) void k_scat(
    const u32* __restrict__ bucketBuf,
    int* __restrict__ deg, u16* __restrict__ csr, u32* __restrict__ spill,
    int* __restrict__ flags) {
  int b = blockIdx.x & 7;
  int cnt = flags[8 + b];
  if (cnt > BCAP) cnt = BCAP;
  const u32* buf = bucketBuf + (long)b * BCAP;
  for (int j = (blockIdx.x >> 3) * 256 + threadIdx.x; j < cnt; j += 65536) {
    u32 e = buf[j];
    int dst = (int)(e >> 16);
    int src = (int)(e & 0xffffu);
    int pos = atomicAdd(&deg[dst], 1);
    if (pos < CAP) csr[(long)dst * CAP + pos] = (u16)src;
    else {
      int sp = atomicAdd(&flags[4], 1);
      spill[sp] = (u32)dst * 50000u + (u32)src;
    }
  }
}

// Fused layer, XCD-feature-partitioned: 2 blocks per 16-node tile.
// half = (blockIdx>>2)&1 == (blockIdx%8)>=4 -> halves live on disjoint XCD
// sets; each half's random gather working set = 50000*64 B = 3.2 MB < 4 MiB L2.
// Each block gathers its half into global agg[NN][64]; the SECOND block to
// finish a tile (atomic ctr) assembles the A tile and runs the MFMA GEMM.
__global__ __launch_bounds__(256, 8) void k_layer(
    const u16* __restrict__ xin_bf, const u16* __restrict__ xin_f32m,
    const u32* __restrict__ xorig32, u32* __restrict__ agg32,
    u16* __restrict__ xout,
    const int* __restrict__ deg, const u16* __restrict__ csr,
    const u32* __restrict__ spill,
    const u16* __restrict__ wfrag, const u16* __restrict__ pfrag,
    const float* __restrict__ bl3, const float* __restrict__ bof,
    void* __restrict__ outp, int layer, int doProj,
    int* __restrict__ tilectr, const int* __restrict__ flags) {
  __shared__ __align__(16) u16 aw[16 * AST];
  __shared__ float sbl[HD];
  __shared__ float sbo[OD];
  __shared__ int swin;
  int tile = (blockIdx.x >> 3) * 4 + (blockIdx.x & 3);
  int h = (blockIdx.x >> 2) & 1;  // feature half; == XCD-group parity
  if (tile >= TILES) return;
  if (threadIdx.x < HD) sbl[threadIdx.x] = bl3[layer * HD + threadIdx.x];
  if (threadIdx.x < OD) sbo[threadIdx.x] = bof[threadIdx.x];
  int lane = threadIdx.x & 63;
  bool f32m = detect_f32(xorig32, lane);
  int spillcnt = __builtin_amdgcn_readfirstlane(flags[4]);
  const u16* xin = f32m ? xin_f32m : xin_bf;
  const u32* x32 = (const u32*)xin;

  int w = threadIdx.x >> 6;
  int nb = tile * 16;
  int n0 = nb + 4 * w;
  int grp = lane >> 3;   // neighbor slot 0..7
  int f = lane & 7;      // 8 B segment of the 64 B half-row

  // ---- degrees + csr rows ----
  int4 dv = *(const int4*)(deg + n0);
  int dt[4] = {__builtin_amdgcn_readfirstlane(dv.x),
               __builtin_amdgcn_readfirstlane(dv.y),
               __builtin_amdgcn_readfirstlane(dv.z),
               __builtin_amdgcn_readfirstlane(dv.w)};
  int d[4], dmax = 0;
  int idx[4];
#pragma unroll
  for (int g = 0; g < 4; ++g) {
    d[g] = dt[g] < CAP ? dt[g] : CAP;
    if (d[g] > dmax) dmax = d[g];
    idx[g] = (lane < d[g]) ? (int)csr[(long)(n0 + g) * CAP + lane] : 0;
  }

  // ---- gather-mean over this block's feature half ----
  const u32x2* xh = (const u32x2*)(x32 + h * 16);  // half-row = 8 u32x2
  float lo[4][2] = {}, hi[4][2] = {};
  for (int j = 0; j < dmax; j += 8) {
    u32x2 v[4];
#pragma unroll
    for (int g = 0; g < 4; ++g) {
      int s = __shfl(idx[g], j + grp);
      v[g] = xh[(long)s * 16 + f];
    }
#pragma unroll
    for (int g = 0; g < 4; ++g) {
      bool ok = (j + grp) < d[g];
#pragma unroll
      for (int q = 0; q < 2; ++q) {
        u32 vv = ok ? v[g][q] : 0u;
        lo[g][q] += __uint_as_float(vv << 16);
        hi[g][q] += __uint_as_float(vv & 0xffff0000u);
      }
    }
  }
#pragma unroll
  for (int g = 0; g < 4; ++g)
#pragma unroll
    for (int q = 0; q < 2; ++q) {
      lo[g][q] += __shfl_xor(lo[g][q], 8);
      hi[g][q] += __shfl_xor(hi[g][q], 8);
      lo[g][q] += __shfl_xor(lo[g][q], 16);
      hi[g][q] += __shfl_xor(hi[g][q], 16);
      lo[g][q] += __shfl_xor(lo[g][q], 32);
      hi[g][q] += __shfl_xor(hi[g][q], 32);
    }
  if (spillcnt > 0) {  // cold path
#pragma unroll
    for (int g = 0; g < 4; ++g) {
      int n = n0 + g;
      for (int base = 0; base < spillcnt; base += 64) {
        u32 p = (base + lane < spillcnt) ? spill[base + lane] : 0xffffffffu;
        u32 dd = p / 50000u;
        u32 ss = p - dd * 50000u;
        unsigned long long mk = __ballot(dd == (u32)n);
        while (mk) {
          int jj = __builtin_ctzll(mk);
          mk &= mk - 1;
          int s = __builtin_amdgcn_readlane((int)ss, jj);
          u32x2 v = xh[(long)s * 16 + f];
#pragma unroll
          for (int q = 0; q < 2; ++q) {
            lo[g][q] += __uint_as_float(v[q] << 16);
            hi[g][q] += __uint_as_float(v[q] & 0xffff0000u);
          }
        }
      }
    }
  }
  if (lane < 8) {  // lane f writes u32x2 seg f of this half
#pragma unroll
    for (int g = 0; g < 4; ++g) {
      float rd = 1.0f / (float)(dt[g] > 0 ? dt[g] : 1);
      u32x2 pk;
      pk[0] = (u32)f2bf(lo[g][0] * rd) | ((u32)f2bf(hi[g][0] * rd) << 16);
      pk[1] = (u32)f2bf(lo[g][1] * rd) | ((u32)f2bf(hi[g][1] * rd) << 16);
      *(u32x2*)(agg32 + (long)(n0 + g) * 32 + h * 16 + 2 * f) = pk;
    }
  }

  // ---- tile pairing: second finisher runs the GEMM ----
  __threadfence();          // release agg writes (device scope)
  __syncthreads();
  if (threadIdx.x == 0) swin = atomicAdd(&tilectr[tile], 1);
  __syncthreads();
  if (swin != 1) return;    // first finisher exits
  __threadfence();          // acquire other half's agg writes

  // ---- assemble A tile from agg (both halves) ----
  {
    int r = threadIdx.x >> 4, seg = threadIdx.x & 15;  // 16 rows x 16 u32x2
    u32x2 v = *(const u32x2*)(agg32 + (long)(nb + r) * 32 + 2 * seg);
    *(u32x2*)((u32*)aw + r * (AST / 2) + 2 * seg) = v;
  }
  __syncthreads();

  int quad = lane >> 4, m16 = lane & 15;
  short8 a0 = *(const short8*)(aw + m16 * AST + quad * 8);        // k 0..31
  short8 a1 = *(const short8*)(aw + m16 * AST + 32 + quad * 8);   // k 32..63
  const u16* xrow = xin + (long)(nb + m16) * HD;
  short8 x2 = *(const short8*)(xrow + quad * 8);                  // k 64..95
  short8 x3 = *(const short8*)(xrow + 32 + quad * 8);             // k 96..127
  int c = w;  // this wave's col-tile
  const short8* bp = (const short8*)(wfrag + (long)layer * 16 * 64 * 8);
  short8 b0 = bp[(0 * 4 + c) * 64 + lane];
  short8 b1 = bp[(1 * 4 + c) * 64 + lane];
  short8 b2 = bp[(2 * 4 + c) * 64 + lane];
  short8 b3 = bp[(3 * 4 + c) * 64 + lane];
  float bb = sbl[c * 16 + m16];
  f32x4 acc = (f32x4){bb, bb, bb, bb};
  acc = __builtin_amdgcn_mfma_f32_16x16x32_bf16(a0, b0, acc, 0, 0, 0);
  acc = __builtin_amdgcn_mfma_f32_16x16x32_bf16(a1, b1, acc, 0, 0, 0);
  acc = __builtin_amdgcn_mfma_f32_16x16x32_bf16(x2, b2, acc, 0, 0, 0);
  acc = __builtin_amdgcn_mfma_f32_16x16x32_bf16(x3, b3, acc, 0, 0, 0);
  __syncthreads();  // all A reads done before C overwrites aw

  // ---- relu -> C staging (C layout: col=lane&15, row=quad*4+reg) ----
#pragma unroll
  for (int r = 0; r < 4; ++r)
    aw[(quad * 4 + r) * AST + c * 16 + m16] = f2bf(fmaxf(acc[r], 0.f));
  __syncthreads();

  if (!doProj) {
    int row = threadIdx.x >> 4, ch = threadIdx.x & 15;
    u32x2 v = *(const u32x2*)(aw + row * AST + ch * 4);
    *(u32x2*)(xout + (long)(nb + row) * HD + ch * 4) = v;
  } else if (w == 0) {
    short8 pa0 = *(const short8*)(aw + m16 * AST + quad * 8);
    short8 pa1 = *(const short8*)(aw + m16 * AST + 32 + quad * 8);
    const short8* pb = (const short8*)pfrag;
    short8 pb0 = pb[lane];
    short8 pb1 = pb[64 + lane];
    float bv = sbo[m16];
    f32x4 pacc = (f32x4){bv, bv, bv, bv};
    pacc = __builtin_amdgcn_mfma_f32_16x16x32_bf16(pa0, pb0, pacc, 0, 0, 0);
    pacc = __builtin_amdgcn_mfma_f32_16x16x32_bf16(pa1, pb1, pacc, 0, 0, 0);
    if (f32m) {
      float* o = (float*)outp;
#pragma unroll
      for (int r = 0; r < 4; ++r)
        o[(long)(nb + quad * 4 + r) * OD + m16] = pacc[r];
    } else {
      u16* o = (u16*)outp;
#pragma unroll
      for (int r = 0; r < 4; ++r)
        o[(long)(nb + quad * 4 + r) * OD + m16] = f2bf(pacc[r]);
    }
  }
}

extern "C" void kernel_launch(void* const* d_in, const int* in_sizes, int n_in,
                              void* d_out, int out_size, void* d_ws, size_t ws_size,
                              hipStream_t stream) {
  const void* x = d_in[0];
  const void* eidx = d_in[1];
  const void* Wl = d_in[2];
  const void* bl = d_in[3];
  const void* Wr = d_in[4];
  const void* Wo = d_in[5];
  const void* bo = d_in[6];

  char* w = (char*)d_ws;
  size_t off = 0;
  int* flags = (int*)(w + off);     off += 256;   // [4]=spill [8..15]=bucketCnt
  int* deg = (int*)(w + off);       off += (size_t)NN * 4 + 192;
  int* tilectr = (int*)(w + off);   off += 3200 * 4;  // per-tile pairing ctr (x3 layers -> reuse? NO: one per layer)
  int* tilectr1 = (int*)(w + off);  off += 3200 * 4;
  int* tilectr2 = (int*)(w + off);  off += 3200 * 4;
  size_t memset_bytes = off;                      // one memset: flags+deg+ctrs
  u32* bucketBuf = (u32*)(w + off); off += (size_t)8 * BCAP * 4;  // 4 MB
  u16* csr = (u16*)(w + off);       off += (size_t)NN * CAP * 2;  // 6.4 MB
  u32* spill = (u32*)(w + off);     off += (size_t)NE * 4;        // 3.2 MB
  u32* agg32 = (u32*)(w + off);     off += (size_t)NN * 32 * 4;   // 6.4 MB
  u16* wfrag = (u16*)(w + off);     off += 3 * 16 * 64 * 8 * 2;
  u16* pfrag = (u16*)(w + off);     off += 2 * 64 * 8 * 2;
  float* blf = (float*)(w + off);   off += 3 * HD * 4;
  float* bof = (float*)(w + off);   off += 256;
  u16* xA = (u16*)(w + off);        off += (size_t)NN * HD * 2;
  u16* xB = (u16*)(w + off);        off += (size_t)NN * HD * 2;

  hipMemsetAsync(flags, 0, memset_bytes, stream);

  k_pre<<<3125, 256, 0, stream>>>(x, eidx, Wl, bl, Wr, Wo, bo,
                                  deg, csr, spill, bucketBuf,
                                  xA, wfrag, pfrag, blf, bof, flags);
  k_scat<<<2048, 256, 0, stream>>>(bucketBuf, deg, csr, spill, flags);

  const u32* xo32 = (const u32*)x;
  const u16* x16 = (const u16*)x;
  // L0: (x|xA) -> xB ; L1: xB -> xA ; L2: xA -> d_out (fused projection)
  k_layer<<<LBLK, 256, 0, stream>>>(x16, xA, xo32, agg32, xB, deg, csr, spill,
                                    wfrag, pfrag, blf, bof, (void*)0, 0, 0,
                                    tilectr, flags);
  k_layer<<<LBLK, 256, 0, stream>>>(xB, xB, xo32, agg32, xA, deg, csr, spill,
                                    wfrag, pfrag, blf, bof, (void*)0, 1, 0,
                                    tilectr1, flags);
  k_layer<<<LBLK, 256, 0, stream>>>(xA, xA, xo32, agg32, (u16*)0, deg, csr, spill,
                                    wfrag, pfrag, blf, bof, d_out, 2, 1,
                                    tilectr2, flags);
}